// Round 3
// baseline (579.184 us; speedup 1.0000x reference)
//
#include <hip/hip_runtime.h>
#include <hip/hip_bf16.h>

#define PTOT   32768
#define KNB    16
#define NCLOUD 16
#define OUTC   512
#define A1S    168   // sa2 A1 row stride in ushort (336 B, 16B-aligned)
#define A2S    264   // sa2 A2 row stride in ushort (528 B, 16B-aligned)

typedef __attribute__((ext_vector_type(8)))  short v8bf;
typedef __attribute__((ext_vector_type(16))) float v16f;

__device__ __forceinline__ unsigned short f2b(float v) {
    __hip_bfloat16 h = __float2bfloat16(v);
    return *reinterpret_cast<unsigned short*>(&h);
}
__device__ __forceinline__ unsigned pk2(float a, float b) {
    return (unsigned)f2b(a) | ((unsigned)f2b(b) << 16);
}
__device__ __forceinline__ unsigned fenc(float f) {
    unsigned u = __float_as_uint(f);
    return (u & 0x80000000u) ? ~u : (u | 0x80000000u);
}
__device__ __forceinline__ float fdec(unsigned u) {
    unsigned b = (u & 0x80000000u) ? (u & 0x7FFFFFFFu) : ~u;
    return __uint_as_float(b);
}
__device__ __forceinline__ v16f zero16() {
    v16f z;
    #pragma unroll
    for (int i = 0; i < 16; ++i) z[i] = 0.0f;
    return z;
}

// ======= prep: k-major bf16 fragment images of W3, W4, W1 (pad K 3->16), W2 ==
__global__ void prep_kernel(const float* __restrict__ W1, const float* __restrict__ W2,
                            const float* __restrict__ W3, const float* __restrict__ W4,
                            unsigned short* __restrict__ W1s, unsigned short* __restrict__ W2s,
                            unsigned short* __restrict__ W3s, unsigned short* __restrict__ W4s)
{
    int i = blockIdx.x * 256 + threadIdx.x;
    if (i < 40960) {                         // W3s[(c2*256+n)*8+j] = W3[c2*8+j][n]
        int j = i & 7, n = (i >> 3) & 255, c2 = i >> 11;
        int k = c2 * 8 + j;
        W3s[i] = f2b(k < 131 ? W3[k * 256 + n] : 0.0f);
    }
    int i2 = i - 40960;
    if (i2 >= 0 && i2 < 131072) {            // W4s[(c2*512+n)*8+j] = W4[c2*8+j][n]
        int j = i2 & 7, n = (i2 >> 3) & 511, c2 = i2 >> 12;
        int k = c2 * 8 + j;
        W4s[i2] = f2b(W4[k * 512 + n]);
    }
    int i3 = i - 172032;
    if (i3 >= 0 && i3 < 1024) {              // W1s[n*16+k] = W1[k][n] (k<3) else 0
        int k = i3 & 15, n = i3 >> 4;
        W1s[i3] = f2b(k < 3 ? W1[k * 64 + n] : 0.0f);
    }
    int i4 = i - 173056;
    if (i4 >= 0 && i4 < 8192) {              // W2s[n*64+k] = W2[k][n]
        int k = i4 & 63, n = i4 >> 6;
        W2s[i4] = f2b(W2[k * 128 + n]);
    }
}

// ======= sa1 (MFMA): block = 4 points (M=64 rows), 256 threads = 4 waves =====
// GEMM1: [64 x 16] diff(pad) @ [16 x 64] W1 -> relu -> A2 in LDS
// GEMM2: [64 x 64] A2 @ [64 x 128] W2 -> max over 16-row groups -> x1b bf16
__global__ __launch_bounds__(256) void sa1_kernel(
    const float* __restrict__ pos, const int* __restrict__ nbr,
    const unsigned short* __restrict__ W1s, const float* __restrict__ b1,
    const unsigned short* __restrict__ W2s, const float* __restrict__ b2,
    unsigned short* __restrict__ x1b)
{
    __shared__ unsigned short A1d[64 * 16];   // 2 KB, row stride 32 B
    __shared__ unsigned short A2[64 * 72];    // 9 KB, row stride 144 B (16B-aligned)
    const int tid  = threadIdx.x;
    const int lane = tid & 63;
    const int wave = tid >> 6;
    const int l31  = lane & 31;
    const int h    = lane >> 5;
    const int p0   = blockIdx.x * 4;

    // stage diffs (rows = point*16 + nbr)
    if (tid < 64) {
        int r = tid;
        int j = nbr[p0 * KNB + r];
        int p = p0 + (r >> 4);
        v8bf z;
        #pragma unroll
        for (int i = 0; i < 8; ++i) z[i] = 0;
        v8bf dv = z;
        dv[0] = (short)f2b(pos[j * 3 + 0] - pos[p * 3 + 0]);
        dv[1] = (short)f2b(pos[j * 3 + 1] - pos[p * 3 + 1]);
        dv[2] = (short)f2b(pos[j * 3 + 2] - pos[p * 3 + 2]);
        *(v8bf*)(A1d + r * 16)     = dv;
        *(v8bf*)(A1d + r * 16 + 8) = z;
    }
    // GEMM1 B-fragment: wave tile (tiler = wave&1 rows, tilec = wave>>1 cols)
    const int c1 = (wave >> 1) * 32 + l31;
    v8bf b1f = *(const v8bf*)(W1s + c1 * 16 + h * 8);
    const float b1v = b1[c1];
    __syncthreads();

    // GEMM1: single MFMA per wave
    {
        v8bf a = *(const v8bf*)(A1d + ((wave & 1) * 32 + l31) * 16 + h * 8);
        v16f acc = __builtin_amdgcn_mfma_f32_32x32x16_bf16(a, b1f, zero16(), 0, 0, 0);
        #pragma unroll
        for (int r = 0; r < 16; ++r) {
            int row = (wave & 1) * 32 + (r & 3) + 8 * (r >> 2) + 4 * h;
            A2[row * 72 + c1] = f2b(fmaxf(acc[r] + b1v, 0.0f));
        }
    }
    // GEMM2 B-fragments (wave owns cols wave*32..+32)
    v8bf B2[4];
    #pragma unroll
    for (int kc = 0; kc < 4; ++kc)
        B2[kc] = *(const v8bf*)(W2s + (wave * 32 + l31) * 64 + kc * 16 + h * 8);
    const float b2v = b2[wave * 32 + l31];
    __syncthreads();

    #pragma unroll
    for (int rt = 0; rt < 2; ++rt) {
        v16f acc = zero16();
        #pragma unroll
        for (int kc = 0; kc < 4; ++kc) {
            v8bf a = *(const v8bf*)(A2 + (rt * 32 + l31) * 72 + kc * 16 + h * 8);
            acc = __builtin_amdgcn_mfma_f32_32x32x16_bf16(a, B2[kc], acc, 0, 0, 0);
        }
        // rows rt*32+0..15 = point p0+rt*2, rows 16..31 = p0+rt*2+1
        float ma = acc[0], mb = acc[8];
        #pragma unroll
        for (int r = 1; r < 8; ++r) { ma = fmaxf(ma, acc[r]); mb = fmaxf(mb, acc[8 + r]); }
        ma = fmaxf(ma, __shfl_xor(ma, 32));
        mb = fmaxf(mb, __shfl_xor(mb, 32));
        int p = p0 + rt * 2 + h;                 // h=0 -> first point, h=1 -> second
        float m = h ? mb : ma;
        x1b[p * 128 + wave * 32 + l31] = f2b(m + b2v);
    }
}

// ==== sa2 (MFMA): 4 points (M=64), 256 thr; A1/A2 share one LDS buffer ======
__global__ __launch_bounds__(256, 4) void sa2_kernel(
    const float* __restrict__ pos, const int* __restrict__ nbr,
    const int* __restrict__ batch,
    const unsigned short* __restrict__ W3s, const float* __restrict__ b3,
    const unsigned short* __restrict__ W4s, const float* __restrict__ b4,
    const unsigned short* __restrict__ x1b, unsigned* __restrict__ encbuf)
{
    __shared__ unsigned short S[64 * A2S];   // 33792 B: A1 (stride A1S) then A2 (stride A2S)
    const int tid  = threadIdx.x;
    const int lane = tid & 63;
    const int wave = tid >> 6;
    const int l31  = lane & 31;
    const int h    = lane >> 5;
    const int p0   = blockIdx.x * 4;

    // GEMM1 B-fragments (wave owns cols [wave*64, wave*64+64))
    v8bf B1[2][10];
    #pragma unroll
    for (int ci = 0; ci < 2; ++ci) {
        int n = (wave * 2 + ci) * 32 + l31;
        #pragma unroll
        for (int kc = 0; kc < 10; ++kc) {
            int c2 = kc * 2 + h;
            B1[ci][kc] = *(const v8bf*)(W3s + ((c2 * 256 + n) << 3));
        }
    }
    const float b3v0 = b3[(wave * 2 + 0) * 32 + l31];
    const float b3v1 = b3[(wave * 2 + 1) * 32 + l31];

    // stage A1: rows = (point, nbr); cols 0..127 x1_j, 128..130 diff, ..159 zero
    {
        int r = tid >> 2, q4 = tid & 3;
        int j = nbr[p0 * KNB + r];
        const uint4* src = (const uint4*)(x1b + j * 128 + q4 * 32);
        uint4* dst = (uint4*)(S + r * A1S + q4 * 32);
        dst[0] = src[0]; dst[1] = src[1]; dst[2] = src[2]; dst[3] = src[3];
    }
    if (tid < 64) {
        int r = tid;
        int j = nbr[p0 * KNB + r];
        int p = p0 + (r >> 4);
        v8bf z;
        #pragma unroll
        for (int i = 0; i < 8; ++i) z[i] = 0;
        v8bf dv = z;
        dv[0] = (short)f2b(pos[j * 3 + 0] - pos[p * 3 + 0]);
        dv[1] = (short)f2b(pos[j * 3 + 1] - pos[p * 3 + 1]);
        dv[2] = (short)f2b(pos[j * 3 + 2] - pos[p * 3 + 2]);
        *(v8bf*)(S + r * A1S + 128) = dv;
        *(v8bf*)(S + r * A1S + 136) = z;
        *(v8bf*)(S + r * A1S + 144) = z;
        *(v8bf*)(S + r * A1S + 152) = z;
    }
    __syncthreads();

    // GEMM1: accumulate both ci, stash bias+relu results as packed bf16
    unsigned st[2][16];
    #pragma unroll
    for (int ci = 0; ci < 2; ++ci) {
        v16f acc0 = zero16(), acc1 = zero16();
        #pragma unroll
        for (int kc = 0; kc < 10; ++kc) {
            v8bf a0 = *(const v8bf*)(S + (l31)      * A1S + kc * 16 + h * 8);
            v8bf a1 = *(const v8bf*)(S + (32 + l31) * A1S + kc * 16 + h * 8);
            acc0 = __builtin_amdgcn_mfma_f32_32x32x16_bf16(a0, B1[ci][kc], acc0, 0, 0, 0);
            acc1 = __builtin_amdgcn_mfma_f32_32x32x16_bf16(a1, B1[ci][kc], acc1, 0, 0, 0);
        }
        float bv = ci ? b3v1 : b3v0;
        #pragma unroll
        for (int i = 0; i < 8; ++i) {
            st[ci][i]     = pk2(fmaxf(acc0[2 * i] + bv, 0.0f), fmaxf(acc0[2 * i + 1] + bv, 0.0f));
            st[ci][8 + i] = pk2(fmaxf(acc1[2 * i] + bv, 0.0f), fmaxf(acc1[2 * i + 1] + bv, 0.0f));
        }
    }
    __syncthreads();   // all A1 reads complete — safe to overwrite with A2

    // store A2 = bf16(relu(GEMM1)) row-major, stride A2S
    #pragma unroll
    for (int ci = 0; ci < 2; ++ci) {
        int c = (wave * 2 + ci) * 32 + l31;
        #pragma unroll
        for (int i = 0; i < 8; ++i) {
            int row = ((2 * i) & 3) + 8 * ((2 * i) >> 2) + 4 * h;  // rows row,row+1
            S[row * A2S + c]            = (unsigned short)(st[ci][i] & 0xFFFF);
            S[(row + 1) * A2S + c]      = (unsigned short)(st[ci][i] >> 16);
            S[(32 + row) * A2S + c]     = (unsigned short)(st[ci][8 + i] & 0xFFFF);
            S[(32 + row + 1) * A2S + c] = (unsigned short)(st[ci][8 + i] >> 16);
        }
    }

    // GEMM2 B-fragments for first ct-pair
    v8bf B2a[16], B2b[16];
    {
        int n0 = (wave * 4) * 32 + l31;
        #pragma unroll
        for (int kc = 0; kc < 16; ++kc) {
            int c2 = kc * 2 + h;
            B2a[kc] = *(const v8bf*)(W4s + ((c2 * 512 + n0) << 3));
            B2b[kc] = *(const v8bf*)(W4s + ((c2 * 512 + n0 + 32) << 3));
        }
    }
    __syncthreads();   // A2 ready

    const int cloud = batch[p0];
    #pragma unroll
    for (int ctp = 0; ctp < 2; ++ctp) {
        if (ctp == 1) {
            int n0 = (wave * 4 + 2) * 32 + l31;
            #pragma unroll
            for (int kc = 0; kc < 16; ++kc) {
                int c2 = kc * 2 + h;
                B2a[kc] = *(const v8bf*)(W4s + ((c2 * 512 + n0) << 3));
                B2b[kc] = *(const v8bf*)(W4s + ((c2 * 512 + n0 + 32) << 3));
            }
        }
        float rm0 = -3.4e38f, rm1 = -3.4e38f;
        #pragma unroll
        for (int rt = 0; rt < 2; ++rt) {
            v16f acc0 = zero16(), acc1 = zero16();
            #pragma unroll
            for (int kc = 0; kc < 16; ++kc) {
                v8bf a = *(const v8bf*)(S + (rt * 32 + l31) * A2S + kc * 16 + h * 8);
                acc0 = __builtin_amdgcn_mfma_f32_32x32x16_bf16(a, B2a[kc], acc0, 0, 0, 0);
                acc1 = __builtin_amdgcn_mfma_f32_32x32x16_bf16(a, B2b[kc], acc1, 0, 0, 0);
            }
            float m0 = acc0[0], m1 = acc1[0];
            #pragma unroll
            for (int r = 1; r < 16; ++r) { m0 = fmaxf(m0, acc0[r]); m1 = fmaxf(m1, acc1[r]); }
            rm0 = fmaxf(rm0, m0);
            rm1 = fmaxf(rm1, m1);
        }
        rm0 = fmaxf(rm0, __shfl_xor(rm0, 32));
        rm1 = fmaxf(rm1, __shfl_xor(rm1, 32));
        int ct0 = wave * 4 + ctp * 2;
        rm0 += b4[ct0 * 32 + l31];
        rm1 += b4[(ct0 + 1) * 32 + l31];
        if (lane < 32) {
            atomicMax(&encbuf[cloud * OUTC + ct0 * 32 + l31], fenc(rm0));
            atomicMax(&encbuf[cloud * OUTC + (ct0 + 1) * 32 + l31], fenc(rm1));
        }
    }
}

// ============================ finalize: decode encoded maxima ================
__global__ void finalize_kernel(const unsigned* __restrict__ encv,
                                float* __restrict__ out)
{
    int i = blockIdx.x * 256 + threadIdx.x;
    if (i < NCLOUD * OUTC) out[i] = fdec(encv[i]);
}

extern "C" void kernel_launch(void* const* d_in, const int* in_sizes, int n_in,
                              void* d_out, int out_size, void* d_ws, size_t ws_size,
                              hipStream_t stream)
{
    const float* pos   = (const float*)d_in[0];
    const int*   nbr   = (const int*)  d_in[1];
    const int*   batch = (const int*)  d_in[2];
    const float* W1    = (const float*)d_in[3];
    const float* b1    = (const float*)d_in[4];
    const float* W2    = (const float*)d_in[5];
    const float* b2    = (const float*)d_in[6];
    const float* W3    = (const float*)d_in[7];
    const float* b3    = (const float*)d_in[8];
    const float* W4    = (const float*)d_in[9];
    const float* b4    = (const float*)d_in[10];

    unsigned short* x1b = (unsigned short*)d_ws;                          // 8 MB
    unsigned short* W3s = (unsigned short*)((char*)d_ws + 8388608);       // 80 KB
    unsigned short* W4s = (unsigned short*)((char*)d_ws + 8470528);       // 256 KB
    unsigned*    encbuf = (unsigned*)((char*)d_ws + 8732672);             // 32 KB
    unsigned short* W1s = (unsigned short*)((char*)d_ws + 8765440);       // 2 KB
    unsigned short* W2s = (unsigned short*)((char*)d_ws + 8767488);       // 16 KB

    hipMemsetAsync(encbuf, 0, NCLOUD * OUTC * sizeof(unsigned), stream);
    prep_kernel<<<708, 256, 0, stream>>>(W1, W2, W3, W4, W1s, W2s, W3s, W4s);
    sa1_kernel<<<PTOT / 4, 256, 0, stream>>>(pos, nbr, W1s, b1, W2s, b2, x1b);
    sa2_kernel<<<PTOT / 4, 256, 0, stream>>>(pos, nbr, batch, W3s, b3, W4s, b4, x1b, encbuf);
    finalize_kernel<<<(NCLOUD * OUTC + 255) / 256, 256, 0, stream>>>(encbuf, (float*)d_out);
}

// Round 4
// 292.326 us; speedup vs baseline: 1.9813x; 1.9813x over previous
//
#include <hip/hip_runtime.h>
#include <hip/hip_bf16.h>

#define PTOT   32768
#define KNB    16
#define NCLOUD 16
#define OUTC   512
#define A1S    168   // sa2 A1 row stride in ushort (336 B, 16B-aligned)
#define A2S    264   // sa2 A2 row stride in ushort (528 B, 16B-aligned)

typedef __attribute__((ext_vector_type(8)))  short v8bf;
typedef __attribute__((ext_vector_type(16))) float v16f;

__device__ __forceinline__ unsigned short f2b(float v) {
    __hip_bfloat16 h = __float2bfloat16(v);
    return *reinterpret_cast<unsigned short*>(&h);
}
__device__ __forceinline__ unsigned pk2(float a, float b) {
    return (unsigned)f2b(a) | ((unsigned)f2b(b) << 16);
}
__device__ __forceinline__ unsigned fenc(float f) {
    unsigned u = __float_as_uint(f);
    return (u & 0x80000000u) ? ~u : (u | 0x80000000u);
}
__device__ __forceinline__ float fdec(unsigned u) {
    unsigned b = (u & 0x80000000u) ? (u & 0x7FFFFFFFu) : ~u;
    return __uint_as_float(b);
}
__device__ __forceinline__ v16f zero16() {
    v16f z;
    #pragma unroll
    for (int i = 0; i < 16; ++i) z[i] = 0.0f;
    return z;
}

// ======= prep: k-major bf16 fragment images of W3, W4, W1 (pad K 3->16), W2 ==
__global__ void prep_kernel(const float* __restrict__ W1, const float* __restrict__ W2,
                            const float* __restrict__ W3, const float* __restrict__ W4,
                            unsigned short* __restrict__ W1s, unsigned short* __restrict__ W2s,
                            unsigned short* __restrict__ W3s, unsigned short* __restrict__ W4s)
{
    int i = blockIdx.x * 256 + threadIdx.x;
    if (i < 40960) {                         // W3s[(c2*256+n)*8+j] = W3[c2*8+j][n]
        int j = i & 7, n = (i >> 3) & 255, c2 = i >> 11;
        int k = c2 * 8 + j;
        W3s[i] = f2b(k < 131 ? W3[k * 256 + n] : 0.0f);
    }
    int i2 = i - 40960;
    if (i2 >= 0 && i2 < 131072) {            // W4s[(c2*512+n)*8+j] = W4[c2*8+j][n]
        int j = i2 & 7, n = (i2 >> 3) & 511, c2 = i2 >> 12;
        int k = c2 * 8 + j;
        W4s[i2] = f2b(W4[k * 512 + n]);
    }
    int i3 = i - 172032;
    if (i3 >= 0 && i3 < 1024) {              // W1s[n*16+k] = W1[k][n] (k<3) else 0
        int k = i3 & 15, n = i3 >> 4;
        W1s[i3] = f2b(k < 3 ? W1[k * 64 + n] : 0.0f);
    }
    int i4 = i - 173056;
    if (i4 >= 0 && i4 < 8192) {              // W2s[n*64+k] = W2[k][n]
        int k = i4 & 63, n = i4 >> 6;
        W2s[i4] = f2b(W2[k * 128 + n]);
    }
}

// ======= sa1 (MFMA): block = 4 points (M=64 rows), 256 threads = 4 waves =====
__global__ __launch_bounds__(256) void sa1_kernel(
    const float* __restrict__ pos, const int* __restrict__ nbr,
    const unsigned short* __restrict__ W1s, const float* __restrict__ b1,
    const unsigned short* __restrict__ W2s, const float* __restrict__ b2,
    unsigned short* __restrict__ x1b)
{
    __shared__ unsigned short A1d[64 * 16];   // 2 KB
    __shared__ unsigned short A2[64 * 72];    // 9 KB
    const int tid  = threadIdx.x;
    const int lane = tid & 63;
    const int wave = tid >> 6;
    const int l31  = lane & 31;
    const int h    = lane >> 5;
    const int p0   = blockIdx.x * 4;

    if (tid < 64) {
        int r = tid;
        int j = nbr[p0 * KNB + r];
        int p = p0 + (r >> 4);
        v8bf z;
        #pragma unroll
        for (int i = 0; i < 8; ++i) z[i] = 0;
        v8bf dv = z;
        dv[0] = (short)f2b(pos[j * 3 + 0] - pos[p * 3 + 0]);
        dv[1] = (short)f2b(pos[j * 3 + 1] - pos[p * 3 + 1]);
        dv[2] = (short)f2b(pos[j * 3 + 2] - pos[p * 3 + 2]);
        *(v8bf*)(A1d + r * 16)     = dv;
        *(v8bf*)(A1d + r * 16 + 8) = z;
    }
    const int c1 = (wave >> 1) * 32 + l31;
    v8bf b1f = *(const v8bf*)(W1s + c1 * 16 + h * 8);
    const float b1v = b1[c1];
    __syncthreads();

    {
        v8bf a = *(const v8bf*)(A1d + ((wave & 1) * 32 + l31) * 16 + h * 8);
        v16f acc = __builtin_amdgcn_mfma_f32_32x32x16_bf16(a, b1f, zero16(), 0, 0, 0);
        #pragma unroll
        for (int r = 0; r < 16; ++r) {
            int row = (wave & 1) * 32 + (r & 3) + 8 * (r >> 2) + 4 * h;
            A2[row * 72 + c1] = f2b(fmaxf(acc[r] + b1v, 0.0f));
        }
    }
    v8bf B2[4];
    #pragma unroll
    for (int kc = 0; kc < 4; ++kc)
        B2[kc] = *(const v8bf*)(W2s + (wave * 32 + l31) * 64 + kc * 16 + h * 8);
    const float b2v = b2[wave * 32 + l31];
    __syncthreads();

    #pragma unroll
    for (int rt = 0; rt < 2; ++rt) {
        v16f acc = zero16();
        #pragma unroll
        for (int kc = 0; kc < 4; ++kc) {
            v8bf a = *(const v8bf*)(A2 + (rt * 32 + l31) * 72 + kc * 16 + h * 8);
            acc = __builtin_amdgcn_mfma_f32_32x32x16_bf16(a, B2[kc], acc, 0, 0, 0);
        }
        float ma = acc[0], mb = acc[8];
        #pragma unroll
        for (int r = 1; r < 8; ++r) { ma = fmaxf(ma, acc[r]); mb = fmaxf(mb, acc[8 + r]); }
        ma = fmaxf(ma, __shfl_xor(ma, 32));
        mb = fmaxf(mb, __shfl_xor(mb, 32));
        int p = p0 + rt * 2 + h;
        float m = h ? mb : ma;
        x1b[p * 128 + wave * 32 + l31] = f2b(m + b2v);
    }
}

// ==== sa2 (MFMA): 4 points (M=64), 256 thr; A1/A2 share LDS; lean registers ==
__global__ __launch_bounds__(256, 2) void sa2_kernel(
    const float* __restrict__ pos, const int* __restrict__ nbr,
    const int* __restrict__ batch,
    const unsigned short* __restrict__ W3s, const float* __restrict__ b3,
    const unsigned short* __restrict__ W4s, const float* __restrict__ b4,
    const unsigned short* __restrict__ x1b, unsigned* __restrict__ encbuf)
{
    __shared__ unsigned short S[64 * A2S];   // 33792 B: A1 (stride A1S) then A2 (stride A2S)
    const int tid  = threadIdx.x;
    const int lane = tid & 63;
    const int wave = tid >> 6;
    const int l31  = lane & 31;
    const int h    = lane >> 5;
    const int p0   = blockIdx.x * 4;

    // ---- prefetch GEMM1 B-fragments for ci=0 (overlaps A1 global staging)
    v8bf B1f[10];
    #pragma unroll
    for (int kc = 0; kc < 10; ++kc) {
        int c2 = kc * 2 + h;
        int n = (wave * 2) * 32 + l31;
        B1f[kc] = *(const v8bf*)(W3s + ((c2 * 256 + n) << 3));
    }
    const float b3v0 = b3[(wave * 2 + 0) * 32 + l31];
    const float b3v1 = b3[(wave * 2 + 1) * 32 + l31];

    // ---- stage A1: rows = (point, nbr); cols 0..127 x1_j, 128..130 diff, ..159 zero
    {
        int r = tid >> 2, q4 = tid & 3;
        int j = nbr[p0 * KNB + r];
        const uint4* src = (const uint4*)(x1b + j * 128 + q4 * 32);
        uint4* dst = (uint4*)(S + r * A1S + q4 * 32);
        dst[0] = src[0]; dst[1] = src[1]; dst[2] = src[2]; dst[3] = src[3];
    }
    if (tid < 64) {
        int r = tid;
        int j = nbr[p0 * KNB + r];
        int p = p0 + (r >> 4);
        v8bf z;
        #pragma unroll
        for (int i = 0; i < 8; ++i) z[i] = 0;
        v8bf dv = z;
        dv[0] = (short)f2b(pos[j * 3 + 0] - pos[p * 3 + 0]);
        dv[1] = (short)f2b(pos[j * 3 + 1] - pos[p * 3 + 1]);
        dv[2] = (short)f2b(pos[j * 3 + 2] - pos[p * 3 + 2]);
        *(v8bf*)(S + r * A1S + 128) = dv;
        *(v8bf*)(S + r * A1S + 136) = z;
        *(v8bf*)(S + r * A1S + 144) = z;
        *(v8bf*)(S + r * A1S + 152) = z;
    }
    __syncthreads();

    // ---- GEMM1: two col-tiles (ci), B1 reloaded per ci to cap pressure
    unsigned st[2][16];
    #pragma unroll
    for (int ci = 0; ci < 2; ++ci) {
        if (ci == 1) {
            #pragma unroll
            for (int kc = 0; kc < 10; ++kc) {
                int c2 = kc * 2 + h;
                int n = (wave * 2 + 1) * 32 + l31;
                B1f[kc] = *(const v8bf*)(W3s + ((c2 * 256 + n) << 3));
            }
        }
        v16f acc0 = zero16(), acc1 = zero16();
        #pragma unroll
        for (int kc = 0; kc < 10; ++kc) {
            v8bf a0 = *(const v8bf*)(S + (l31)      * A1S + kc * 16 + h * 8);
            v8bf a1 = *(const v8bf*)(S + (32 + l31) * A1S + kc * 16 + h * 8);
            acc0 = __builtin_amdgcn_mfma_f32_32x32x16_bf16(a0, B1f[kc], acc0, 0, 0, 0);
            acc1 = __builtin_amdgcn_mfma_f32_32x32x16_bf16(a1, B1f[kc], acc1, 0, 0, 0);
        }
        float bv = ci ? b3v1 : b3v0;
        #pragma unroll
        for (int i = 0; i < 8; ++i) {
            st[ci][i]     = pk2(fmaxf(acc0[2 * i] + bv, 0.0f), fmaxf(acc0[2 * i + 1] + bv, 0.0f));
            st[ci][8 + i] = pk2(fmaxf(acc1[2 * i] + bv, 0.0f), fmaxf(acc1[2 * i + 1] + bv, 0.0f));
        }
    }
    __syncthreads();   // all A1 reads complete — safe to overwrite with A2

    // ---- store A2 = bf16(relu(GEMM1)) row-major, stride A2S
    #pragma unroll
    for (int ci = 0; ci < 2; ++ci) {
        int c = (wave * 2 + ci) * 32 + l31;
        #pragma unroll
        for (int i = 0; i < 8; ++i) {
            int row = ((2 * i) & 3) + 8 * ((2 * i) >> 2) + 4 * h;
            S[row * A2S + c]            = (unsigned short)(st[ci][i] & 0xFFFF);
            S[(row + 1) * A2S + c]      = (unsigned short)(st[ci][i] >> 16);
            S[(32 + row) * A2S + c]     = (unsigned short)(st[ci][8 + i] & 0xFFFF);
            S[(32 + row + 1) * A2S + c] = (unsigned short)(st[ci][8 + i] >> 16);
        }
    }

    // ---- prefetch GEMM2 B-fragments for ctp=0 (overlaps A2 LDS writes)
    v8bf B2[16];
    {
        int n0 = (wave * 4) * 32 + l31;
        #pragma unroll
        for (int kc = 0; kc < 16; ++kc) {
            int c2 = kc * 2 + h;
            B2[kc] = *(const v8bf*)(W4s + ((c2 * 512 + n0) << 3));
        }
    }
    __syncthreads();   // A2 ready

    const int cloud = batch[p0];
    #pragma unroll
    for (int ctp = 0; ctp < 4; ++ctp) {
        if (ctp > 0) {
            int n0 = (wave * 4 + ctp) * 32 + l31;
            #pragma unroll
            for (int kc = 0; kc < 16; ++kc) {
                int c2 = kc * 2 + h;
                B2[kc] = *(const v8bf*)(W4s + ((c2 * 512 + n0) << 3));
            }
        }
        v16f acc0 = zero16(), acc1 = zero16();
        #pragma unroll
        for (int kc = 0; kc < 16; ++kc) {
            v8bf a0 = *(const v8bf*)(S + (l31)      * A2S + kc * 16 + h * 8);
            v8bf a1 = *(const v8bf*)(S + (32 + l31) * A2S + kc * 16 + h * 8);
            acc0 = __builtin_amdgcn_mfma_f32_32x32x16_bf16(a0, B2[kc], acc0, 0, 0, 0);
            acc1 = __builtin_amdgcn_mfma_f32_32x32x16_bf16(a1, B2[kc], acc1, 0, 0, 0);
        }
        float m0 = acc0[0];
        #pragma unroll
        for (int r = 1; r < 16; ++r) m0 = fmaxf(m0, acc0[r]);
        #pragma unroll
        for (int r = 0; r < 16; ++r) m0 = fmaxf(m0, acc1[r]);
        m0 = fmaxf(m0, __shfl_xor(m0, 32));
        int ct = wave * 4 + ctp;
        m0 += b4[ct * 32 + l31];
        if (lane < 32) atomicMax(&encbuf[cloud * OUTC + ct * 32 + l31], fenc(m0));
    }
}

// ============================ finalize: decode encoded maxima ================
__global__ void finalize_kernel(const unsigned* __restrict__ encv,
                                float* __restrict__ out)
{
    int i = blockIdx.x * 256 + threadIdx.x;
    if (i < NCLOUD * OUTC) out[i] = fdec(encv[i]);
}

extern "C" void kernel_launch(void* const* d_in, const int* in_sizes, int n_in,
                              void* d_out, int out_size, void* d_ws, size_t ws_size,
                              hipStream_t stream)
{
    const float* pos   = (const float*)d_in[0];
    const int*   nbr   = (const int*)  d_in[1];
    const int*   batch = (const int*)  d_in[2];
    const float* W1    = (const float*)d_in[3];
    const float* b1    = (const float*)d_in[4];
    const float* W2    = (const float*)d_in[5];
    const float* b2    = (const float*)d_in[6];
    const float* W3    = (const float*)d_in[7];
    const float* b3    = (const float*)d_in[8];
    const float* W4    = (const float*)d_in[9];
    const float* b4    = (const float*)d_in[10];

    unsigned short* x1b = (unsigned short*)d_ws;                          // 8 MB
    unsigned short* W3s = (unsigned short*)((char*)d_ws + 8388608);       // 80 KB
    unsigned short* W4s = (unsigned short*)((char*)d_ws + 8470528);       // 256 KB
    unsigned*    encbuf = (unsigned*)((char*)d_ws + 8732672);             // 32 KB
    unsigned short* W1s = (unsigned short*)((char*)d_ws + 8765440);       // 2 KB
    unsigned short* W2s = (unsigned short*)((char*)d_ws + 8767488);       // 16 KB

    hipMemsetAsync(encbuf, 0, NCLOUD * OUTC * sizeof(unsigned), stream);
    prep_kernel<<<708, 256, 0, stream>>>(W1, W2, W3, W4, W1s, W2s, W3s, W4s);
    sa1_kernel<<<PTOT / 4, 256, 0, stream>>>(pos, nbr, W1s, b1, W2s, b2, x1b);
    sa2_kernel<<<PTOT / 4, 256, 0, stream>>>(pos, nbr, batch, W3s, b3, W4s, b4, x1b, encbuf);
    finalize_kernel<<<(NCLOUD * OUTC + 255) / 256, 256, 0, stream>>>(encbuf, (float*)d_out);
}

// Round 5
// 288.101 us; speedup vs baseline: 2.0104x; 1.0147x over previous
//
#include <hip/hip_runtime.h>
#include <hip/hip_bf16.h>

#define PTOT   32768
#define KNB    16
#define NCLOUD 16
#define OUTC   512
#define A1S    168   // sa2 A1 row stride in ushort (336 B, 16B-aligned)
#define A2S    264   // sa2 A2 row stride in ushort (528 B, 16B-aligned)

typedef __attribute__((ext_vector_type(8)))  short v8bf;
typedef __attribute__((ext_vector_type(16))) float v16f;

__device__ __forceinline__ unsigned short f2b(float v) {
    __hip_bfloat16 h = __float2bfloat16(v);
    return *reinterpret_cast<unsigned short*>(&h);
}
__device__ __forceinline__ unsigned pk2(float a, float b) {
    return (unsigned)f2b(a) | ((unsigned)f2b(b) << 16);
}
__device__ __forceinline__ unsigned fenc(float f) {
    unsigned u = __float_as_uint(f);
    return (u & 0x80000000u) ? ~u : (u | 0x80000000u);
}
__device__ __forceinline__ float fdec(unsigned u) {
    unsigned b = (u & 0x80000000u) ? (u & 0x7FFFFFFFu) : ~u;
    return __uint_as_float(b);
}
__device__ __forceinline__ v16f zero16() {
    v16f z;
    #pragma unroll
    for (int i = 0; i < 16; ++i) z[i] = 0.0f;
    return z;
}

// ======= prep: k-major bf16 fragment images of W3, W4, W1 (pad K 3->16), W2 ==
__global__ void prep_kernel(const float* __restrict__ W1, const float* __restrict__ W2,
                            const float* __restrict__ W3, const float* __restrict__ W4,
                            unsigned short* __restrict__ W1s, unsigned short* __restrict__ W2s,
                            unsigned short* __restrict__ W3s, unsigned short* __restrict__ W4s)
{
    int i = blockIdx.x * 256 + threadIdx.x;
    if (i < 40960) {                         // W3s[(c2*256+n)*8+j] = W3[c2*8+j][n]
        int j = i & 7, n = (i >> 3) & 255, c2 = i >> 11;
        int k = c2 * 8 + j;
        W3s[i] = f2b(k < 131 ? W3[k * 256 + n] : 0.0f);
    }
    int i2 = i - 40960;
    if (i2 >= 0 && i2 < 131072) {            // W4s[(c2*512+n)*8+j] = W4[c2*8+j][n]
        int j = i2 & 7, n = (i2 >> 3) & 511, c2 = i2 >> 12;
        int k = c2 * 8 + j;
        W4s[i2] = f2b(W4[k * 512 + n]);
    }
    int i3 = i - 172032;
    if (i3 >= 0 && i3 < 1024) {              // W1s[n*16+k] = W1[k][n] (k<3) else 0
        int k = i3 & 15, n = i3 >> 4;
        W1s[i3] = f2b(k < 3 ? W1[k * 64 + n] : 0.0f);
    }
    int i4 = i - 173056;
    if (i4 >= 0 && i4 < 8192) {              // W2s[n*64+k] = W2[k][n]
        int k = i4 & 63, n = i4 >> 6;
        W2s[i4] = f2b(W2[k * 128 + n]);
    }
}

// ======= sa1 (MFMA): block = 4 points (M=64 rows), 256 threads = 4 waves =====
__global__ __launch_bounds__(256) void sa1_kernel(
    const float* __restrict__ pos, const int* __restrict__ nbr,
    const unsigned short* __restrict__ W1s, const float* __restrict__ b1,
    const unsigned short* __restrict__ W2s, const float* __restrict__ b2,
    unsigned short* __restrict__ x1b)
{
    __shared__ unsigned short A1d[64 * 16];   // 2 KB
    __shared__ unsigned short A2[64 * 72];    // 9 KB
    const int tid  = threadIdx.x;
    const int lane = tid & 63;
    const int wave = tid >> 6;
    const int l31  = lane & 31;
    const int h    = lane >> 5;
    const int p0   = blockIdx.x * 4;

    if (tid < 64) {
        int r = tid;
        int j = nbr[p0 * KNB + r];
        int p = p0 + (r >> 4);
        v8bf z;
        #pragma unroll
        for (int i = 0; i < 8; ++i) z[i] = 0;
        v8bf dv = z;
        dv[0] = (short)f2b(pos[j * 3 + 0] - pos[p * 3 + 0]);
        dv[1] = (short)f2b(pos[j * 3 + 1] - pos[p * 3 + 1]);
        dv[2] = (short)f2b(pos[j * 3 + 2] - pos[p * 3 + 2]);
        *(v8bf*)(A1d + r * 16)     = dv;
        *(v8bf*)(A1d + r * 16 + 8) = z;
    }
    const int c1 = (wave >> 1) * 32 + l31;
    v8bf b1f = *(const v8bf*)(W1s + c1 * 16 + h * 8);
    const float b1v = b1[c1];
    __syncthreads();

    {
        v8bf a = *(const v8bf*)(A1d + ((wave & 1) * 32 + l31) * 16 + h * 8);
        v16f acc = __builtin_amdgcn_mfma_f32_32x32x16_bf16(a, b1f, zero16(), 0, 0, 0);
        #pragma unroll
        for (int r = 0; r < 16; ++r) {
            int row = (wave & 1) * 32 + (r & 3) + 8 * (r >> 2) + 4 * h;
            A2[row * 72 + c1] = f2b(fmaxf(acc[r] + b1v, 0.0f));
        }
    }
    v8bf B2[4];
    #pragma unroll
    for (int kc = 0; kc < 4; ++kc)
        B2[kc] = *(const v8bf*)(W2s + (wave * 32 + l31) * 64 + kc * 16 + h * 8);
    const float b2v = b2[wave * 32 + l31];
    __syncthreads();

    #pragma unroll
    for (int rt = 0; rt < 2; ++rt) {
        v16f acc = zero16();
        #pragma unroll
        for (int kc = 0; kc < 4; ++kc) {
            v8bf a = *(const v8bf*)(A2 + (rt * 32 + l31) * 72 + kc * 16 + h * 8);
            acc = __builtin_amdgcn_mfma_f32_32x32x16_bf16(a, B2[kc], acc, 0, 0, 0);
        }
        float ma = acc[0], mb = acc[8];
        #pragma unroll
        for (int r = 1; r < 8; ++r) { ma = fmaxf(ma, acc[r]); mb = fmaxf(mb, acc[8 + r]); }
        ma = fmaxf(ma, __shfl_xor(ma, 32));
        mb = fmaxf(mb, __shfl_xor(mb, 32));
        int p = p0 + rt * 2 + h;
        float m = h ? mb : ma;
        x1b[p * 128 + wave * 32 + l31] = f2b(m + b2v);
    }
}

// ==== sa2 (MFMA): 4 points (M=64), 256 thr; kc-outer, streamed B, 1:2 reuse ==
__global__ __launch_bounds__(256) void sa2_kernel(
    const float* __restrict__ pos, const int* __restrict__ nbr,
    const int* __restrict__ batch,
    const unsigned short* __restrict__ W3s, const float* __restrict__ b3,
    const unsigned short* __restrict__ W4s, const float* __restrict__ b4,
    const unsigned short* __restrict__ x1b, unsigned* __restrict__ encbuf)
{
    __shared__ unsigned short S[64 * A2S];   // 33792 B: A1 (stride A1S) then A2 (stride A2S)
    const int tid  = threadIdx.x;
    const int lane = tid & 63;
    const int wave = tid >> 6;
    const int l31  = lane & 31;
    const int h    = lane >> 5;
    const int p0   = blockIdx.x * 4;

    const float b3v0 = b3[(wave * 2 + 0) * 32 + l31];
    const float b3v1 = b3[(wave * 2 + 1) * 32 + l31];

    // ---- stage A1: rows = (point, nbr); cols 0..127 x1_j, 128..130 diff, ..159 zero
    {
        int r = tid >> 2, q4 = tid & 3;
        int j = nbr[p0 * KNB + r];
        const uint4* src = (const uint4*)(x1b + j * 128 + q4 * 32);
        uint4* dst = (uint4*)(S + r * A1S + q4 * 32);
        dst[0] = src[0]; dst[1] = src[1]; dst[2] = src[2]; dst[3] = src[3];
    }
    if (tid < 64) {
        int r = tid;
        int j = nbr[p0 * KNB + r];
        int p = p0 + (r >> 4);
        v8bf z;
        #pragma unroll
        for (int i = 0; i < 8; ++i) z[i] = 0;
        v8bf dv = z;
        dv[0] = (short)f2b(pos[j * 3 + 0] - pos[p * 3 + 0]);
        dv[1] = (short)f2b(pos[j * 3 + 1] - pos[p * 3 + 1]);
        dv[2] = (short)f2b(pos[j * 3 + 2] - pos[p * 3 + 2]);
        *(v8bf*)(S + r * A1S + 128) = dv;
        *(v8bf*)(S + r * A1S + 136) = z;
        *(v8bf*)(S + r * A1S + 144) = z;
        *(v8bf*)(S + r * A1S + 152) = z;
    }
    __syncthreads();

    // ---- GEMM1: kc-outer; one A-read pair feeds both ci col-tiles (4 MFMAs)
    // kc=9 (k=144..159) is all-zero pad on both sides -> skipped.
    v16f g00 = zero16(), g01 = zero16(), g10 = zero16(), g11 = zero16();
    const int n1a = (wave * 2 + 0) * 32 + l31;
    const int n1b = (wave * 2 + 1) * 32 + l31;
    #pragma unroll
    for (int kc = 0; kc < 9; ++kc) {
        v8bf a0 = *(const v8bf*)(S + (l31)      * A1S + kc * 16 + h * 8);
        v8bf a1 = *(const v8bf*)(S + (32 + l31) * A1S + kc * 16 + h * 8);
        int c2 = kc * 2 + h;
        v8bf B0 = *(const v8bf*)(W3s + ((c2 * 256 + n1a) << 3));
        v8bf B1 = *(const v8bf*)(W3s + ((c2 * 256 + n1b) << 3));
        g00 = __builtin_amdgcn_mfma_f32_32x32x16_bf16(a0, B0, g00, 0, 0, 0);
        g10 = __builtin_amdgcn_mfma_f32_32x32x16_bf16(a1, B0, g10, 0, 0, 0);
        g01 = __builtin_amdgcn_mfma_f32_32x32x16_bf16(a0, B1, g01, 0, 0, 0);
        g11 = __builtin_amdgcn_mfma_f32_32x32x16_bf16(a1, B1, g11, 0, 0, 0);
    }
    // pack bias+relu results as bf16 pairs
    unsigned st[2][16];
    #pragma unroll
    for (int i = 0; i < 8; ++i) {
        st[0][i]     = pk2(fmaxf(g00[2 * i] + b3v0, 0.0f), fmaxf(g00[2 * i + 1] + b3v0, 0.0f));
        st[0][8 + i] = pk2(fmaxf(g10[2 * i] + b3v0, 0.0f), fmaxf(g10[2 * i + 1] + b3v0, 0.0f));
        st[1][i]     = pk2(fmaxf(g01[2 * i] + b3v1, 0.0f), fmaxf(g01[2 * i + 1] + b3v1, 0.0f));
        st[1][8 + i] = pk2(fmaxf(g11[2 * i] + b3v1, 0.0f), fmaxf(g11[2 * i + 1] + b3v1, 0.0f));
    }
    __syncthreads();   // all A1 reads complete — safe to overwrite with A2

    // ---- store A2 = bf16(relu(GEMM1)) row-major, stride A2S
    #pragma unroll
    for (int ci = 0; ci < 2; ++ci) {
        int c = (wave * 2 + ci) * 32 + l31;
        #pragma unroll
        for (int i = 0; i < 8; ++i) {
            int row = ((2 * i) & 3) + 8 * ((2 * i) >> 2) + 4 * h;
            S[row * A2S + c]            = (unsigned short)(st[ci][i] & 0xFFFF);
            S[(row + 1) * A2S + c]      = (unsigned short)(st[ci][i] >> 16);
            S[(32 + row) * A2S + c]     = (unsigned short)(st[ci][8 + i] & 0xFFFF);
            S[(32 + row + 1) * A2S + c] = (unsigned short)(st[ci][8 + i] >> 16);
        }
    }
    __syncthreads();   // A2 ready

    // ---- GEMM2: 2 passes of ct-pairs; kc-outer, streamed B, 1:2 A reuse
    const int cloud = batch[p0];
    #pragma unroll
    for (int pass = 0; pass < 2; ++pass) {
        const int ct0 = wave * 4 + pass * 2;
        const int n0 = ct0 * 32 + l31;
        const int n1 = (ct0 + 1) * 32 + l31;
        v16f a00 = zero16(), a01 = zero16(), a10 = zero16(), a11 = zero16();
        #pragma unroll
        for (int kc = 0; kc < 16; ++kc) {
            v8bf a0 = *(const v8bf*)(S + (l31)      * A2S + kc * 16 + h * 8);
            v8bf a1 = *(const v8bf*)(S + (32 + l31) * A2S + kc * 16 + h * 8);
            int c2 = kc * 2 + h;
            v8bf Ba = *(const v8bf*)(W4s + ((c2 * 512 + n0) << 3));
            v8bf Bb = *(const v8bf*)(W4s + ((c2 * 512 + n1) << 3));
            a00 = __builtin_amdgcn_mfma_f32_32x32x16_bf16(a0, Ba, a00, 0, 0, 0);
            a10 = __builtin_amdgcn_mfma_f32_32x32x16_bf16(a1, Ba, a10, 0, 0, 0);
            a01 = __builtin_amdgcn_mfma_f32_32x32x16_bf16(a0, Bb, a01, 0, 0, 0);
            a11 = __builtin_amdgcn_mfma_f32_32x32x16_bf16(a1, Bb, a11, 0, 0, 0);
        }
        float m0 = a00[0], m1 = a01[0];
        #pragma unroll
        for (int r = 1; r < 16; ++r) { m0 = fmaxf(m0, a00[r]); m1 = fmaxf(m1, a01[r]); }
        #pragma unroll
        for (int r = 0; r < 16; ++r) { m0 = fmaxf(m0, a10[r]); m1 = fmaxf(m1, a11[r]); }
        m0 = fmaxf(m0, __shfl_xor(m0, 32));
        m1 = fmaxf(m1, __shfl_xor(m1, 32));
        m0 += b4[ct0 * 32 + l31];
        m1 += b4[(ct0 + 1) * 32 + l31];
        if (lane < 32) {
            atomicMax(&encbuf[cloud * OUTC + ct0 * 32 + l31], fenc(m0));
            atomicMax(&encbuf[cloud * OUTC + (ct0 + 1) * 32 + l31], fenc(m1));
        }
    }
}

// ============================ finalize: decode encoded maxima ================
__global__ void finalize_kernel(const unsigned* __restrict__ encv,
                                float* __restrict__ out)
{
    int i = blockIdx.x * 256 + threadIdx.x;
    if (i < NCLOUD * OUTC) out[i] = fdec(encv[i]);
}

extern "C" void kernel_launch(void* const* d_in, const int* in_sizes, int n_in,
                              void* d_out, int out_size, void* d_ws, size_t ws_size,
                              hipStream_t stream)
{
    const float* pos   = (const float*)d_in[0];
    const int*   nbr   = (const int*)  d_in[1];
    const int*   batch = (const int*)  d_in[2];
    const float* W1    = (const float*)d_in[3];
    const float* b1    = (const float*)d_in[4];
    const float* W2    = (const float*)d_in[5];
    const float* b2    = (const float*)d_in[6];
    const float* W3    = (const float*)d_in[7];
    const float* b3    = (const float*)d_in[8];
    const float* W4    = (const float*)d_in[9];
    const float* b4    = (const float*)d_in[10];

    unsigned short* x1b = (unsigned short*)d_ws;                          // 8 MB
    unsigned short* W3s = (unsigned short*)((char*)d_ws + 8388608);       // 80 KB
    unsigned short* W4s = (unsigned short*)((char*)d_ws + 8470528);       // 256 KB
    unsigned*    encbuf = (unsigned*)((char*)d_ws + 8732672);             // 32 KB
    unsigned short* W1s = (unsigned short*)((char*)d_ws + 8765440);       // 2 KB
    unsigned short* W2s = (unsigned short*)((char*)d_ws + 8767488);       // 16 KB

    hipMemsetAsync(encbuf, 0, NCLOUD * OUTC * sizeof(unsigned), stream);
    prep_kernel<<<708, 256, 0, stream>>>(W1, W2, W3, W4, W1s, W2s, W3s, W4s);
    sa1_kernel<<<PTOT / 4, 256, 0, stream>>>(pos, nbr, W1s, b1, W2s, b2, x1b);
    sa2_kernel<<<PTOT / 4, 256, 0, stream>>>(pos, nbr, batch, W3s, b3, W4s, b4, x1b, encbuf);
    finalize_kernel<<<(NCLOUD * OUTC + 255) / 256, 256, 0, stream>>>(encbuf, (float*)d_out);
}

// Round 8
// 252.688 us; speedup vs baseline: 2.2921x; 1.1401x over previous
//
#include <hip/hip_runtime.h>
#include <hip/hip_bf16.h>

#define PTOT   32768
#define KNB    16
#define NCLOUD 16
#define OUTC   512
#define A1S    168   // sa2 A1 row stride in ushort (336 B, 16B-aligned)
#define A2S    264   // sa2 A2 row stride in ushort (528 B, 16B-aligned, 4-way-max banks)

typedef __attribute__((ext_vector_type(8)))  short v8bf;
typedef __attribute__((ext_vector_type(16))) float v16f;

__device__ __forceinline__ unsigned short f2b(float v) {
    __hip_bfloat16 h = __float2bfloat16(v);
    return *reinterpret_cast<unsigned short*>(&h);
}
__device__ __forceinline__ unsigned pk2(float a, float b) {
    return (unsigned)f2b(a) | ((unsigned)f2b(b) << 16);
}
__device__ __forceinline__ unsigned fenc(float f) {
    unsigned u = __float_as_uint(f);
    return (u & 0x80000000u) ? ~u : (u | 0x80000000u);
}
__device__ __forceinline__ float fdec(unsigned u) {
    unsigned b = (u & 0x80000000u) ? (u & 0x7FFFFFFFu) : ~u;
    return __uint_as_float(b);
}
__device__ __forceinline__ v16f zero16() {
    v16f z;
    #pragma unroll
    for (int i = 0; i < 16; ++i) z[i] = 0.0f;
    return z;
}

// ======= prep: k-major bf16 fragment images of W3, W4, W1 (pad K 3->16), W2 ==
__global__ void prep_kernel(const float* __restrict__ W1, const float* __restrict__ W2,
                            const float* __restrict__ W3, const float* __restrict__ W4,
                            unsigned short* __restrict__ W1s, unsigned short* __restrict__ W2s,
                            unsigned short* __restrict__ W3s, unsigned short* __restrict__ W4s)
{
    int i = blockIdx.x * 256 + threadIdx.x;
    if (i < 40960) {                         // W3s[(c2*256+n)*8+j] = W3[c2*8+j][n]
        int j = i & 7, n = (i >> 3) & 255, c2 = i >> 11;
        int k = c2 * 8 + j;
        W3s[i] = f2b(k < 131 ? W3[k * 256 + n] : 0.0f);
    }
    int i2 = i - 40960;
    if (i2 >= 0 && i2 < 131072) {            // W4s[(c2*512+n)*8+j] = W4[c2*8+j][n]
        int j = i2 & 7, n = (i2 >> 3) & 511, c2 = i2 >> 12;
        int k = c2 * 8 + j;
        W4s[i2] = f2b(W4[k * 512 + n]);
    }
    int i3 = i - 172032;
    if (i3 >= 0 && i3 < 1024) {              // W1s[n*16+k] = W1[k][n] (k<3) else 0
        int k = i3 & 15, n = i3 >> 4;
        W1s[i3] = f2b(k < 3 ? W1[k * 64 + n] : 0.0f);
    }
    int i4 = i - 173056;
    if (i4 >= 0 && i4 < 8192) {              // W2s[n*64+k] = W2[k][n]
        int k = i4 & 63, n = i4 >> 6;
        W2s[i4] = f2b(W2[k * 128 + n]);
    }
}

// ======= sa1 (MFMA): block = 4 points (M=64 rows), 256 threads = 4 waves =====
__global__ __launch_bounds__(256) void sa1_kernel(
    const float* __restrict__ pos, const int* __restrict__ nbr,
    const unsigned short* __restrict__ W1s, const float* __restrict__ b1,
    const unsigned short* __restrict__ W2s, const float* __restrict__ b2,
    unsigned short* __restrict__ x1b)
{
    __shared__ unsigned short A1d[64 * 16];   // 2 KB
    __shared__ unsigned short A2[64 * 72];    // 9 KB
    const int tid  = threadIdx.x;
    const int lane = tid & 63;
    const int wave = tid >> 6;
    const int l31  = lane & 31;
    const int h    = lane >> 5;
    const int p0   = blockIdx.x * 4;

    if (tid < 64) {
        int r = tid;
        int j = nbr[p0 * KNB + r];
        int p = p0 + (r >> 4);
        v8bf z;
        #pragma unroll
        for (int i = 0; i < 8; ++i) z[i] = 0;
        v8bf dv = z;
        dv[0] = (short)f2b(pos[j * 3 + 0] - pos[p * 3 + 0]);
        dv[1] = (short)f2b(pos[j * 3 + 1] - pos[p * 3 + 1]);
        dv[2] = (short)f2b(pos[j * 3 + 2] - pos[p * 3 + 2]);
        *(v8bf*)(A1d + r * 16)     = dv;
        *(v8bf*)(A1d + r * 16 + 8) = z;
    }
    const int c1 = (wave >> 1) * 32 + l31;
    v8bf b1f = *(const v8bf*)(W1s + c1 * 16 + h * 8);
    const float b1v = b1[c1];
    __syncthreads();

    {
        v8bf a = *(const v8bf*)(A1d + ((wave & 1) * 32 + l31) * 16 + h * 8);
        v16f acc = __builtin_amdgcn_mfma_f32_32x32x16_bf16(a, b1f, zero16(), 0, 0, 0);
        #pragma unroll
        for (int r = 0; r < 16; ++r) {
            int row = (wave & 1) * 32 + (r & 3) + 8 * (r >> 2) + 4 * h;
            A2[row * 72 + c1] = f2b(fmaxf(acc[r] + b1v, 0.0f));
        }
    }
    v8bf B2[4];
    #pragma unroll
    for (int kc = 0; kc < 4; ++kc)
        B2[kc] = *(const v8bf*)(W2s + (wave * 32 + l31) * 64 + kc * 16 + h * 8);
    const float b2v = b2[wave * 32 + l31];
    __syncthreads();

    #pragma unroll
    for (int rt = 0; rt < 2; ++rt) {
        v16f acc = zero16();
        #pragma unroll
        for (int kc = 0; kc < 4; ++kc) {
            v8bf a = *(const v8bf*)(A2 + (rt * 32 + l31) * 72 + kc * 16 + h * 8);
            acc = __builtin_amdgcn_mfma_f32_32x32x16_bf16(a, B2[kc], acc, 0, 0, 0);
        }
        float ma = acc[0], mb = acc[8];
        #pragma unroll
        for (int r = 1; r < 8; ++r) { ma = fmaxf(ma, acc[r]); mb = fmaxf(mb, acc[8 + r]); }
        ma = fmaxf(ma, __shfl_xor(ma, 32));
        mb = fmaxf(mb, __shfl_xor(mb, 32));
        int p = p0 + rt * 2 + h;
        float m = h ? mb : ma;
        x1b[p * 128 + wave * 32 + l31] = f2b(m + b2v);
    }
}

// ==== sa2 (MFMA): 8 points (M=128), 256 thr; padded A2 (stride 264), 67.5 KB =
__global__ __launch_bounds__(256) void sa2_kernel(
    const float* __restrict__ pos, const int* __restrict__ nbr,
    const int* __restrict__ batch,
    const unsigned short* __restrict__ W3s, const float* __restrict__ b3,
    const unsigned short* __restrict__ W4s, const float* __restrict__ b4,
    const unsigned short* __restrict__ x1b, unsigned* __restrict__ encbuf)
{
    __shared__ unsigned short S[128 * A2S];   // 67584 B (gfx950 allows >64K/WG): A1 overlaid
    const int tid  = threadIdx.x;
    const int lane = tid & 63;
    const int wave = tid >> 6;
    const int l31  = lane & 31;
    const int h    = lane >> 5;
    const int p0   = blockIdx.x * 8;

    const float b3v0 = b3[(wave * 2 + 0) * 32 + l31];
    const float b3v1 = b3[(wave * 2 + 1) * 32 + l31];

    // ---- stage A1: 128 rows = (point, nbr); cols 0..127 x1_j, 128..130 diff, ..143 zero
    {
        int r = tid >> 1, q = tid & 1;            // 2 threads/row, each copies 128 B
        int j = nbr[p0 * KNB + r];
        const uint4* src = (const uint4*)(x1b + j * 128 + q * 64);
        uint4* dst = (uint4*)(S + r * A1S + q * 64);
        #pragma unroll
        for (int i = 0; i < 8; ++i) dst[i] = src[i];
    }
    if (tid < 128) {
        int r = tid;
        int j = nbr[p0 * KNB + r];
        int p = p0 + (r >> 4);
        v8bf z;
        #pragma unroll
        for (int i = 0; i < 8; ++i) z[i] = 0;
        v8bf dv = z;
        dv[0] = (short)f2b(pos[j * 3 + 0] - pos[p * 3 + 0]);
        dv[1] = (short)f2b(pos[j * 3 + 1] - pos[p * 3 + 1]);
        dv[2] = (short)f2b(pos[j * 3 + 2] - pos[p * 3 + 2]);
        *(v8bf*)(S + r * A1S + 128) = dv;
        *(v8bf*)(S + r * A1S + 136) = z;
    }
    __syncthreads();

    // ---- GEMM1: kc-streamed B (R5-proven), looped over 2 row-tile-pairs
    // kc=9 (k=144..159) all-zero pad -> skipped.
    const int n1a = (wave * 2 + 0) * 32 + l31;
    const int n1b = (wave * 2 + 1) * 32 + l31;
    unsigned stA[2][16], stB[2][16];   // [rtp][..] ci=0 / ci=1
    #pragma unroll
    for (int rtp = 0; rtp < 2; ++rtp) {
        v16f g00 = zero16(), g01 = zero16(), g10 = zero16(), g11 = zero16();
        #pragma unroll
        for (int kc = 0; kc < 9; ++kc) {
            v8bf a0 = *(const v8bf*)(S + (rtp * 64 + l31)      * A1S + kc * 16 + h * 8);
            v8bf a1 = *(const v8bf*)(S + (rtp * 64 + 32 + l31) * A1S + kc * 16 + h * 8);
            int c2 = kc * 2 + h;
            v8bf B0 = *(const v8bf*)(W3s + ((c2 * 256 + n1a) << 3));
            v8bf B1 = *(const v8bf*)(W3s + ((c2 * 256 + n1b) << 3));
            g00 = __builtin_amdgcn_mfma_f32_32x32x16_bf16(a0, B0, g00, 0, 0, 0);
            g10 = __builtin_amdgcn_mfma_f32_32x32x16_bf16(a1, B0, g10, 0, 0, 0);
            g01 = __builtin_amdgcn_mfma_f32_32x32x16_bf16(a0, B1, g01, 0, 0, 0);
            g11 = __builtin_amdgcn_mfma_f32_32x32x16_bf16(a1, B1, g11, 0, 0, 0);
        }
        #pragma unroll
        for (int i = 0; i < 8; ++i) {
            stA[rtp][i]     = pk2(fmaxf(g00[2*i] + b3v0, 0.0f), fmaxf(g00[2*i+1] + b3v0, 0.0f));
            stA[rtp][8 + i] = pk2(fmaxf(g10[2*i] + b3v0, 0.0f), fmaxf(g10[2*i+1] + b3v0, 0.0f));
            stB[rtp][i]     = pk2(fmaxf(g01[2*i] + b3v1, 0.0f), fmaxf(g01[2*i+1] + b3v1, 0.0f));
            stB[rtp][8 + i] = pk2(fmaxf(g11[2*i] + b3v1, 0.0f), fmaxf(g11[2*i+1] + b3v1, 0.0f));
        }
    }
    __syncthreads();   // all A1 reads complete — safe to overwrite with A2

    // ---- store A2 = bf16(relu(GEMM1)) row-major, stride A2S (R5-proven formula)
    {
        const int c0 = (wave * 2 + 0) * 32 + l31;
        const int c1 = (wave * 2 + 1) * 32 + l31;
        #pragma unroll
        for (int rtp = 0; rtp < 2; ++rtp) {
            const int rb = rtp * 64;
            #pragma unroll
            for (int i = 0; i < 8; ++i) {
                int row = rb + ((2*i) & 3) + 8 * ((2*i) >> 2) + 4 * h;
                S[row * A2S + c0]        = (unsigned short)(stA[rtp][i] & 0xFFFF);
                S[(row + 1) * A2S + c0]  = (unsigned short)(stA[rtp][i] >> 16);
                S[(row + 32) * A2S + c0] = (unsigned short)(stA[rtp][8 + i] & 0xFFFF);
                S[(row + 33) * A2S + c0] = (unsigned short)(stA[rtp][8 + i] >> 16);
                S[row * A2S + c1]        = (unsigned short)(stB[rtp][i] & 0xFFFF);
                S[(row + 1) * A2S + c1]  = (unsigned short)(stB[rtp][i] >> 16);
                S[(row + 32) * A2S + c1] = (unsigned short)(stB[rtp][8 + i] & 0xFFFF);
                S[(row + 33) * A2S + c1] = (unsigned short)(stB[rtp][8 + i] >> 16);
            }
        }
    }
    __syncthreads();   // A2 ready

    // ---- GEMM2: ct-pair outer (B held, reused by both row-tile-pairs)
    const int cloud = batch[p0];
    #pragma unroll
    for (int cp = 0; cp < 2; ++cp) {
        const int ct0 = wave * 4 + cp * 2;
        const int n0 = ct0 * 32 + l31;
        const int n1 = (ct0 + 1) * 32 + l31;
        v8bf B2a[16], B2b[16];
        #pragma unroll
        for (int kc = 0; kc < 16; ++kc) {
            int c2 = kc * 2 + h;
            B2a[kc] = *(const v8bf*)(W4s + ((c2 * 512 + n0) << 3));
            B2b[kc] = *(const v8bf*)(W4s + ((c2 * 512 + n1) << 3));
        }
        float rm0 = -3.4e38f, rm1 = -3.4e38f;
        #pragma unroll
        for (int rtp = 0; rtp < 2; ++rtp) {
            v16f a00 = zero16(), a01 = zero16(), a10 = zero16(), a11 = zero16();
            #pragma unroll
            for (int kc = 0; kc < 16; ++kc) {
                v8bf a0 = *(const v8bf*)(S + (rtp * 64 + l31)      * A2S + kc * 16 + h * 8);
                v8bf a1 = *(const v8bf*)(S + (rtp * 64 + 32 + l31) * A2S + kc * 16 + h * 8);
                a00 = __builtin_amdgcn_mfma_f32_32x32x16_bf16(a0, B2a[kc], a00, 0, 0, 0);
                a10 = __builtin_amdgcn_mfma_f32_32x32x16_bf16(a1, B2a[kc], a10, 0, 0, 0);
                a01 = __builtin_amdgcn_mfma_f32_32x32x16_bf16(a0, B2b[kc], a01, 0, 0, 0);
                a11 = __builtin_amdgcn_mfma_f32_32x32x16_bf16(a1, B2b[kc], a11, 0, 0, 0);
            }
            #pragma unroll
            for (int r = 0; r < 16; ++r) {
                rm0 = fmaxf(rm0, fmaxf(a00[r], a10[r]));
                rm1 = fmaxf(rm1, fmaxf(a01[r], a11[r]));
            }
        }
        rm0 = fmaxf(rm0, __shfl_xor(rm0, 32));
        rm1 = fmaxf(rm1, __shfl_xor(rm1, 32));
        rm0 += b4[ct0 * 32 + l31];
        rm1 += b4[(ct0 + 1) * 32 + l31];
        if (lane < 32) {
            atomicMax(&encbuf[cloud * OUTC + ct0 * 32 + l31], fenc(rm0));
            atomicMax(&encbuf[cloud * OUTC + (ct0 + 1) * 32 + l31], fenc(rm1));
        }
    }
}

// ============================ finalize: decode encoded maxima ================
__global__ void finalize_kernel(const unsigned* __restrict__ encv,
                                float* __restrict__ out)
{
    int i = blockIdx.x * 256 + threadIdx.x;
    if (i < NCLOUD * OUTC) out[i] = fdec(encv[i]);
}

extern "C" void kernel_launch(void* const* d_in, const int* in_sizes, int n_in,
                              void* d_out, int out_size, void* d_ws, size_t ws_size,
                              hipStream_t stream)
{
    const float* pos   = (const float*)d_in[0];
    const int*   nbr   = (const int*)  d_in[1];
    const int*   batch = (const int*)  d_in[2];
    const float* W1    = (const float*)d_in[3];
    const float* b1    = (const float*)d_in[4];
    const float* W2    = (const float*)d_in[5];
    const float* b2    = (const float*)d_in[6];
    const float* W3    = (const float*)d_in[7];
    const float* b3    = (const float*)d_in[8];
    const float* W4    = (const float*)d_in[9];
    const float* b4    = (const float*)d_in[10];

    unsigned short* x1b = (unsigned short*)d_ws;                          // 8 MB
    unsigned short* W3s = (unsigned short*)((char*)d_ws + 8388608);       // 80 KB
    unsigned short* W4s = (unsigned short*)((char*)d_ws + 8470528);       // 256 KB
    unsigned*    encbuf = (unsigned*)((char*)d_ws + 8732672);             // 32 KB
    unsigned short* W1s = (unsigned short*)((char*)d_ws + 8765440);       // 2 KB
    unsigned short* W2s = (unsigned short*)((char*)d_ws + 8767488);       // 16 KB

    hipMemsetAsync(encbuf, 0, NCLOUD * OUTC * sizeof(unsigned), stream);
    prep_kernel<<<708, 256, 0, stream>>>(W1, W2, W3, W4, W1s, W2s, W3s, W4s);
    sa1_kernel<<<PTOT / 4, 256, 0, stream>>>(pos, nbr, W1s, b1, W2s, b2, x1b);
    sa2_kernel<<<PTOT / 8, 256, 0, stream>>>(pos, nbr, batch, W3s, b3, W4s, b4, x1b, encbuf);
    finalize_kernel<<<(NCLOUD * OUTC + 255) / 256, 256, 0, stream>>>(encbuf, (float*)d_out);
}